// Round 1
// baseline (1077.543 us; speedup 1.0000x reference)
//
#include <hip/hip_runtime.h>

typedef float v2f __attribute__((ext_vector_type(2)));

#define T_LEN 2048
#define NH    10
#define OUT_T 1439
#define TFIRST 608      // first output timestep (T - TAIL)
#define NSEQ  4096

static __device__ __forceinline__ v2f fma2(v2f a, v2f b, v2f c) {
  return __builtin_elementwise_fma(a, b, c);
}
static __device__ __forceinline__ v2f splat2(float v) { v2f r; r.x = v; r.y = v; return r; }

// sigmoid(z) = 1/(1+exp(-z)) = rcp(1 + exp2(z * -log2(e)))
static __device__ __forceinline__ float fast_sigmoid(float z) {
  float e = __builtin_amdgcn_exp2f(z * -1.4426950408889634f);
  return __builtin_amdgcn_rcpf(1.0f + e);
}
// tanh(z) = 2*sigmoid(2z) - 1 ; exp2 overflow -> Inf -> rcp -> 0 -> -1 (correct saturation)
static __device__ __forceinline__ float fast_tanh(float z) {
  float e = __builtin_amdgcn_exp2f(z * -2.8853900817779268f);
  return __builtin_amdgcn_rcpf(1.0f + e) * 2.0f - 1.0f;
}

#define SWZ(v, patt) __uint_as_float(__builtin_amdgcn_ds_swizzle(__float_as_uint(v), (patt)))

// 4 sequences per wave; 16 lanes per sequence; lane u<10 owns hidden unit u
// (all four gates). Lanes u=10..15 carry the fc1 rows folded into the layer-1
// "g" gate slot (which receives tanh), so the FC head is free.
__global__ void __launch_bounds__(64, 1)
lstm_fused(const float* __restrict__ x,
           const float* __restrict__ w_ih0, const float* __restrict__ w_hh0,
           const float* __restrict__ b_ih0, const float* __restrict__ b_hh0,
           const float* __restrict__ w_ih1, const float* __restrict__ w_hh1,
           const float* __restrict__ b_ih1, const float* __restrict__ b_hh1,
           const float* __restrict__ fc1_w, const float* __restrict__ fc1_b,
           const float* __restrict__ fc2_w, const float* __restrict__ fc2_b,
           float* __restrict__ out)
{
  __shared__ __align__(16) float hb0[64];
  __shared__ __align__(16) float hb1[64];

  const int lane = threadIdx.x;       // 0..63
  const int grp  = lane >> 4;         // sequence within wave (0..3)
  const int u    = lane & 15;         // unit slot within group
  const int seq  = (int)blockIdx.x * 4 + grp;

  // per-lane weights: pairs pack gate (i,f) and (g,o)
  v2f whh0_if[NH], whh0_go[NH], wih1_if[NH], wih1_go[NH], whh1_if[NH], whh1_go[NH];
  v2f b0_if, b0_go, b1_if, b1_go, wx_if, wx_go;
  b0_if = b0_go = b1_if = b1_go = wx_if = wx_go = splat2(0.f);
#pragma unroll
  for (int j = 0; j < NH; ++j) {
    whh0_if[j] = splat2(0.f); whh0_go[j] = splat2(0.f);
    wih1_if[j] = splat2(0.f); wih1_go[j] = splat2(0.f);
    whh1_if[j] = splat2(0.f); whh1_go[j] = splat2(0.f);
  }

  if (u < NH) {
    const int ri = 0*NH+u, rf = 1*NH+u, rg = 2*NH+u, ro = 3*NH+u;
    wx_if.x = w_ih0[ri]; wx_if.y = w_ih0[rf];
    wx_go.x = w_ih0[rg]; wx_go.y = w_ih0[ro];
    b0_if.x = b_ih0[ri] + b_hh0[ri]; b0_if.y = b_ih0[rf] + b_hh0[rf];
    b0_go.x = b_ih0[rg] + b_hh0[rg]; b0_go.y = b_ih0[ro] + b_hh0[ro];
    b1_if.x = b_ih1[ri] + b_hh1[ri]; b1_if.y = b_ih1[rf] + b_hh1[rf];
    b1_go.x = b_ih1[rg] + b_hh1[rg]; b1_go.y = b_ih1[ro] + b_hh1[ro];
#pragma unroll
    for (int j = 0; j < NH; ++j) {
      whh0_if[j].x = w_hh0[ri*NH+j]; whh0_if[j].y = w_hh0[rf*NH+j];
      whh0_go[j].x = w_hh0[rg*NH+j]; whh0_go[j].y = w_hh0[ro*NH+j];
      wih1_if[j].x = w_ih1[ri*NH+j]; wih1_if[j].y = w_ih1[rf*NH+j];
      wih1_go[j].x = w_ih1[rg*NH+j]; wih1_go[j].y = w_ih1[ro*NH+j];
      whh1_if[j].x = w_hh1[ri*NH+j]; whh1_if[j].y = w_hh1[rf*NH+j];
      whh1_go[j].x = w_hh1[rg*NH+j]; whh1_go[j].y = w_hh1[ro*NH+j];
    }
  } else {
    const int j6 = u - NH;            // 0..5
    b1_go.x = fc1_b[j6];              // fc1 folded into L1 "g" slot (gets tanh)
#pragma unroll
    for (int j = 0; j < NH; ++j) whh1_go[j].x = fc1_w[j6*NH + j];
  }

  const float fc2wl = (u >= NH) ? fc2_w[u - NH] : 0.f;
  const float fc2bl = fc2_b[0];
  const float umask = (u < NH) ? 1.f : 0.f;

  const float* xp   = x + (size_t)seq * T_LEN;
  float*       outp = out + (size_t)seq * OUT_T;

  float c0 = 0.f, c1 = 0.f;
  float h0s[NH], h1s[NH];
#pragma unroll
  for (int j = 0; j < NH; ++j) { h0s[j] = 0.f; h1s[j] = 0.f; }

  float xv = xp[0];

#pragma unroll 1
  for (int t = 0; t < T_LEN; ++t) {
    const int tn = (t + 1 < T_LEN) ? (t + 1) : (T_LEN - 1);
    const float xn = xp[tn];                       // prefetch next x

    // ---------------- layer 0 ----------------
    v2f aif = fma2(wx_if, splat2(xv), b0_if);
    v2f ago = fma2(wx_go, splat2(xv), b0_go);
#pragma unroll
    for (int j = 0; j < NH; ++j) {
      const v2f hj = splat2(h0s[j]);
      aif = fma2(whh0_if[j], hj, aif);
      ago = fma2(whh0_go[j], hj, ago);
    }
    const float si = fast_sigmoid(aif.x);
    const float sf = fast_sigmoid(aif.y);
    const float tg = fast_tanh(ago.x);
    const float so = fast_sigmoid(ago.y);
    c0 = sf * c0 + si * tg;
    const float h0n = so * fast_tanh(c0) * umask;  // pad lanes write 0
    hb0[lane] = h0n;                               // same-wave DS is in-order
    {
      const float4 a = *(const float4*)&hb0[grp*16];
      const float4 b = *(const float4*)&hb0[grp*16+4];
      const float2 c = *(const float2*)&hb0[grp*16+8];
      h0s[0]=a.x; h0s[1]=a.y; h0s[2]=a.z; h0s[3]=a.w;
      h0s[4]=b.x; h0s[5]=b.y; h0s[6]=b.z; h0s[7]=b.w;
      h0s[8]=c.x; h0s[9]=c.y;
    }

    // ---------------- layer 1 (+ folded fc1) ----------------
    v2f bif = b1_if, bgo = b1_go;
#pragma unroll
    for (int j = 0; j < NH; ++j) {
      const v2f hj0 = splat2(h0s[j]);
      bif = fma2(wih1_if[j], hj0, bif);
      bgo = fma2(wih1_go[j], hj0, bgo);
    }
#pragma unroll
    for (int j = 0; j < NH; ++j) {
      const v2f hj1 = splat2(h1s[j]);              // h1_{t-1}
      bif = fma2(whh1_if[j], hj1, bif);
      bgo = fma2(whh1_go[j], hj1, bgo);
    }
    const float si1 = fast_sigmoid(bif.x);
    const float sf1 = fast_sigmoid(bif.y);
    const float tg1 = fast_tanh(bgo.x);            // fc lanes: tanh(fc1(h1_{t-1}))
    const float so1 = fast_sigmoid(bgo.y);
    c1 = sf1 * c1 + si1 * tg1;
    const float h1n = so1 * fast_tanh(c1) * umask;
    hb1[lane] = h1n;
    {
      const float4 a = *(const float4*)&hb1[grp*16];
      const float4 b = *(const float4*)&hb1[grp*16+4];
      const float2 c = *(const float2*)&hb1[grp*16+8];
      h1s[0]=a.x; h1s[1]=a.y; h1s[2]=a.z; h1s[3]=a.w;
      h1s[4]=b.x; h1s[5]=b.y; h1s[6]=b.z; h1s[7]=b.w;
      h1s[8]=c.x; h1s[9]=c.y;
    }

    // ---------------- fc2: output for timestep t-1 ----------------
    if (t > TFIRST) {                              // t in [609, 2047] -> out idx 0..1438
      float y = tg1 * fc2wl;                       // zero on lanes u<10
      y += SWZ(y, 0x041F);                         // xor 1
      y += SWZ(y, 0x081F);                         // xor 2
      y += SWZ(y, 0x101F);                         // xor 4 -> lanes 8..15 hold sum
      if (u == 8) outp[t - 1 - TFIRST] = y + fc2bl;
    }

    xv = xn;
  }
}

extern "C" void kernel_launch(void* const* d_in, const int* in_sizes, int n_in,
                              void* d_out, int out_size, void* d_ws, size_t ws_size,
                              hipStream_t stream) {
  const float* x     = (const float*)d_in[0];
  const float* w_ih0 = (const float*)d_in[1];
  const float* w_hh0 = (const float*)d_in[2];
  const float* b_ih0 = (const float*)d_in[3];
  const float* b_hh0 = (const float*)d_in[4];
  const float* w_ih1 = (const float*)d_in[5];
  const float* w_hh1 = (const float*)d_in[6];
  const float* b_ih1 = (const float*)d_in[7];
  const float* b_hh1 = (const float*)d_in[8];
  const float* fc1_w = (const float*)d_in[9];
  const float* fc1_b = (const float*)d_in[10];
  const float* fc2_w = (const float*)d_in[11];
  const float* fc2_b = (const float*)d_in[12];
  float* out = (float*)d_out;

  lstm_fused<<<dim3(NSEQ / 4), dim3(64), 0, stream>>>(
      x, w_ih0, w_hh0, b_ih0, b_hh0, w_ih1, w_hh1, b_ih1, b_hh1,
      fc1_w, fc1_b, fc2_w, fc2_b, out);
}